// Round 13
// baseline (146.515 us; speedup 1.0000x reference)
//
#include <hip/hip_runtime.h>
#include <hip/hip_bf16.h>
#include <math.h>

// Problem constants
#define BB 128
#define KK 32
#define JJ 1152
#define II 8
#define ZZ 16

#define NJG  12            // kA: 12 j-groups; block covers 24 quads (96 j)
#define NJT  144           // kBC: 144 j-tiles of 8 j

typedef __attribute__((ext_vector_type(8))) short short8;
typedef __attribute__((ext_vector_type(4))) float floatx4;

// Workspace float-word layout: [usum | usum_p | sacc_p | xbf | Wt]
#define N_USUM  (KK * BB * ZZ)                   // 65536
#define N_USUMP (NJG * KK * BB * ZZ)             // 786432
#define N_SACCP ((size_t)NJT * KK * BB * ZZ)     // 9437184

#define KX_BLOCKS ((JJ * BB) / 256)              // 576
#define KW_BLOCKS ((KK * JJ * ZZ) / 256)         // 2304

__device__ __forceinline__ float bf2f(short h) {
    unsigned int w = ((unsigned int)(unsigned short)h) << 16;
    float f; __builtin_memcpy(&f, &w, 4);
    return f;
}

// ---- Merged prep: x -> xbf[j][b][i] bf16 ; W -> Wt[k][j][z][i] bf16 ----
extern "C" __global__ __launch_bounds__(256)
void kP(const float* __restrict__ x, const float* __restrict__ W,
        __hip_bfloat16* __restrict__ xbf, __hip_bfloat16* __restrict__ Wt) {
    if (blockIdx.x < KX_BLOCKS) {
        int idx = blockIdx.x * 256 + threadIdx.x;    // [0, J*B)
        int j_in = idx & 15;
        int rest = idx >> 4;
        int b    = rest & 127;
        int j    = (rest >> 7) * 16 + j_in;
        const float4* xp = (const float4*)(x + ((size_t)b * JJ + j) * II);
        float4 a = xp[0], c = xp[1];
        union { short8 v; __hip_bfloat16 h[8]; } u;
        u.h[0] = __float2bfloat16(a.x); u.h[1] = __float2bfloat16(a.y);
        u.h[2] = __float2bfloat16(a.z); u.h[3] = __float2bfloat16(a.w);
        u.h[4] = __float2bfloat16(c.x); u.h[5] = __float2bfloat16(c.y);
        u.h[6] = __float2bfloat16(c.z); u.h[7] = __float2bfloat16(c.w);
        *(short8*)(xbf + ((size_t)j * BB + b) * II) = u.v;
    } else {
        int idx = (blockIdx.x - KX_BLOCKS) * 256 + threadIdx.x;  // [0, K*J*16)
        int z    = idx & 15;
        int rest = idx >> 4;
        int j    = rest % JJ;
        int k    = rest / JJ;
        const float* src = W + (((size_t)k * JJ + j) * II) * ZZ + z;
        union { short8 v; __hip_bfloat16 h[8]; } u;
#pragma unroll
        for (int i = 0; i < II; ++i) u.h[i] = __float2bfloat16(src[i * ZZ]);
        *(short8*)(Wt + (((size_t)k * JJ + j) * ZZ + z) * II) = u.v;
    }
}

// ---- Pass A: usum_p[jg][k][b][z] partials; 4-wave blocks, LDS reduce ----
// grid (8 kt, 4 bt, NJG), block 256. Wave w covers quads jg*24 + w*6 .. +6.
extern "C" __global__ __launch_bounds__(256)
void kA(const __hip_bfloat16* __restrict__ xbf,
        const __hip_bfloat16* __restrict__ Wt, float* __restrict__ usum_p) {
    __shared__ float Ls[4][8][256];    // [w][slot=kk*2+half][lane*4+c] 32 KB
    const int kt = blockIdx.x;
    const int bt = blockIdx.y;
    const int jg = blockIdx.z;
    const int t  = threadIdx.x;
    const int w  = t >> 6;
    const int l  = t & 63;
    const int n  = l & 15;
    const int g  = l >> 4;
    const int b1 = bt * 32 + n;
    const int b2 = b1 + 16;
    const int q0 = jg * 24 + w * 6;

    short8 xv1[6], xv2[6];
#pragma unroll
    for (int q = 0; q < 6; ++q) {
        int j = (q0 + q) * 4 + g;
        xv1[q] = *(const short8*)(xbf + ((size_t)j * BB + b1) * II);
        xv2[q] = *(const short8*)(xbf + ((size_t)j * BB + b2) * II);
    }

    floatx4 acc1[4], acc2[4];
#pragma unroll
    for (int kk = 0; kk < 4; ++kk) {
        acc1[kk] = (floatx4){0.f, 0.f, 0.f, 0.f};
        acc2[kk] = (floatx4){0.f, 0.f, 0.f, 0.f};
    }

#pragma unroll
    for (int kk = 0; kk < 4; ++kk) {
        const int k = kt * 4 + kk;
#pragma unroll
        for (int q = 0; q < 6; ++q) {
            int j = (q0 + q) * 4 + g;
            short8 a = *(const short8*)(Wt + (((size_t)k * JJ + j) * ZZ + n) * II);
            acc1[kk] = __builtin_amdgcn_mfma_f32_16x16x32_bf16(a, xv1[q], acc1[kk], 0, 0, 0);
            acc2[kk] = __builtin_amdgcn_mfma_f32_16x16x32_bf16(a, xv2[q], acc2[kk], 0, 0, 0);
        }
    }
#pragma unroll
    for (int kk = 0; kk < 4; ++kk) {
        *(floatx4*)&Ls[w][kk * 2 + 0][l * 4] = acc1[kk];
        *(floatx4*)&Ls[w][kk * 2 + 1][l * 4] = acc2[kk];
    }
    __syncthreads();
    // Reduce across the 4 waves; 512 (slot,lane) pairs, 2 per thread.
#pragma unroll
    for (int pp = 0; pp < 2; ++pp) {
        int p  = t + pp * 256;
        int s  = p >> 6;
        int ll = p & 63;
        int nn = ll & 15, gg = ll >> 4;
        floatx4 v = *(const floatx4*)&Ls[0][s][ll * 4];
        v += *(const floatx4*)&Ls[1][s][ll * 4];
        v += *(const floatx4*)&Ls[2][s][ll * 4];
        v += *(const floatx4*)&Ls[3][s][ll * 4];
        int k = kt * 4 + (s >> 1);
        int b = bt * 32 + nn + 16 * (s & 1);
        *(floatx4*)(usum_p + (((size_t)jg * KK + k) * BB + b) * ZZ + gg * 4) = v;
    }
}

// ---- kR: usum = sum_jg usum_p. 4-way split + shfl combine ----
extern "C" __global__ __launch_bounds__(256)
void kR(const float* __restrict__ usum_p, float* __restrict__ usum) {
    int p   = blockIdx.x * 256 + threadIdx.x;    // [0, 65536)
    int r   = p & 3;
    int idx = p >> 2;                            // float4 index [0,16384)
    floatx4 s = (floatx4){0.f, 0.f, 0.f, 0.f};
#pragma unroll
    for (int jg = r * 3; jg < r * 3 + 3; ++jg)
        s += *(const floatx4*)(usum_p + (size_t)jg * N_USUM + (size_t)idx * 4);
#pragma unroll
    for (int c = 0; c < 4; ++c) {
        s[c] += __shfl_xor(s[c], 1);
        s[c] += __shfl_xor(s[c], 2);
    }
    if (r == 0) *(floatx4*)(usum + (size_t)idx * 4) = s;
}

// ---- Fused B+C over (8-j, 32-b) tile; 8 waves x 4 k each ----
extern "C" __global__ __launch_bounds__(512)
void kBC(const __hip_bfloat16* __restrict__ xbf,
         const __hip_bfloat16* __restrict__ Wt,
         const float* __restrict__ usum, const float* __restrict__ bias,
         float* __restrict__ sacc_p) {
    __shared__ float eS[KK * 8 * 32];   // 32 KB: e[k][jl][col]
    __shared__ float Sw[8 * 8 * 32];    // 8 KB per-wave S partials
    __shared__ float rS[8 * 32];        // 1 KB: 1/S[jl][col]

    const int jt = blockIdx.x;          // 0..143
    const int bt = blockIdx.y;          // 0..3
    const int t  = threadIdx.x;
    const int w  = t >> 6;              // 0..7 -> k-range w*4..w*4+3
    const int l  = t & 63;
    const int n  = l & 15;
    const int g  = l >> 4;
    const int b1 = bt * 32 + n;
    const int b2 = b1 + 16;
    const int j0 = jt * 8;

    short8 xv1[8], xv2[8];
#pragma unroll
    for (int jl = 0; jl < 8; ++jl) {
        xv1[jl] = *(const short8*)(xbf + ((size_t)(j0 + jl) * BB + b1) * II);
        xv2[jl] = *(const short8*)(xbf + ((size_t)(j0 + jl) * BB + b2) * II);
    }

    // ---- Phase 1: e + per-wave S ----
    float Sacc1[8], Sacc2[8];
#pragma unroll
    for (int jl = 0; jl < 8; ++jl) { Sacc1[jl] = 0.f; Sacc2[jl] = 0.f; }

#pragma unroll 2
    for (int kk = 0; kk < 4; ++kk) {
        const int k = w * 4 + kk;
        floatx4 us1 = *(const floatx4*)(usum + ((size_t)k * BB + b1) * ZZ + g * 4);
        floatx4 us2 = *(const floatx4*)(usum + ((size_t)k * BB + b2) * ZZ + g * 4);
#pragma unroll
        for (int jl = 0; jl < 8; ++jl) {
            short8 a = *(const short8*)(Wt + (((size_t)k * JJ + j0 + jl) * ZZ + n) * II);
            floatx4 c0 = {0.f, 0.f, 0.f, 0.f};
            floatx4 u1 = __builtin_amdgcn_mfma_f32_16x16x32_bf16(a, xv1[jl], c0, 0, 0, 0);
            floatx4 u2 = __builtin_amdgcn_mfma_f32_16x16x32_bf16(a, xv2[jl], c0, 0, 0, 0);
            float dp1 = u1[0] * us1[0];
            dp1 = fmaf(u1[1], us1[1], dp1);
            dp1 = fmaf(u1[2], us1[2], dp1);
            dp1 = fmaf(u1[3], us1[3], dp1);
            float dp2 = u2[0] * us2[0];
            dp2 = fmaf(u2[1], us2[1], dp2);
            dp2 = fmaf(u2[2], us2[2], dp2);
            dp2 = fmaf(u2[3], us2[3], dp2);
            dp1 += __shfl_xor(dp1, 16);
            dp1 += __shfl_xor(dp1, 32);
            dp2 += __shfl_xor(dp2, 16);
            dp2 += __shfl_xor(dp2, 32);
            float e1 = __expf(dp1 * 0.0625f);   // 0.25 softmax * 0.25 K-dup
            float e2 = __expf(dp2 * 0.0625f);
            Sacc1[jl] += e1;
            Sacc2[jl] += e2;
            if (g == 0) {
                eS[(k * 8 + jl) * 32 + n]      = e1;
                eS[(k * 8 + jl) * 32 + n + 16] = e2;
            }
        }
    }
    if (g == 0) {
#pragma unroll
        for (int jl = 0; jl < 8; ++jl) {
            Sw[(w * 8 + jl) * 32 + n]      = Sacc1[jl];
            Sw[(w * 8 + jl) * 32 + n + 16] = Sacc2[jl];
        }
    }
    __syncthreads();
    if (t < 256) {
        int jl = t >> 5, col = t & 31;
        float s = 0.f;
#pragma unroll
        for (int ww = 0; ww < 8; ++ww) s += Sw[(ww * 8 + jl) * 32 + col];
        rS[jl * 32 + col] = __builtin_amdgcn_rcpf(s);
    }
    __syncthreads();

    // ---- Phase 2: sacc partial, c folded into B-operand ----
    float xf1[2][8], xf2[2][8];
#pragma unroll
    for (int quad = 0; quad < 2; ++quad) {
        union { short8 v; short s[8]; } xr1, xr2;
        int j = j0 + quad * 4 + g;
        xr1.v = *(const short8*)(xbf + ((size_t)j * BB + b1) * II);
        xr2.v = *(const short8*)(xbf + ((size_t)j * BB + b2) * II);
#pragma unroll
        for (int i = 0; i < II; ++i) {
            xf1[quad][i] = bf2f(xr1.s[i]);
            xf2[quad][i] = bf2f(xr2.s[i]);
        }
    }

    floatx4 acc1[4], acc2[4];
#pragma unroll
    for (int kk = 0; kk < 4; ++kk) {
        acc1[kk] = (floatx4){0.f, 0.f, 0.f, 0.f};
        acc2[kk] = (floatx4){0.f, 0.f, 0.f, 0.f};
    }

#pragma unroll 2
    for (int kk = 0; kk < 4; ++kk) {
        const int k = w * 4 + kk;
#pragma unroll
        for (int quad = 0; quad < 2; ++quad) {
            const int jl = quad * 4 + g;
            const int j  = j0 + jl;
            float bj = bias[(size_t)k * JJ + j];
            float c1 = fmaf(eS[(k * 8 + jl) * 32 + n],      rS[jl * 32 + n],      bj);
            float c2 = fmaf(eS[(k * 8 + jl) * 32 + n + 16], rS[jl * 32 + n + 16], bj);
            union { short8 v; short s[8]; } xs1, xs2;
#pragma unroll
            for (int i = 0; i < II; ++i) {
                __hip_bfloat16 h1 = __float2bfloat16(xf1[quad][i] * c1);
                __hip_bfloat16 h2 = __float2bfloat16(xf2[quad][i] * c2);
                __builtin_memcpy(&xs1.s[i], &h1, 2);
                __builtin_memcpy(&xs2.s[i], &h2, 2);
            }
            short8 a = *(const short8*)(Wt + (((size_t)k * JJ + j) * ZZ + n) * II);
            acc1[kk] = __builtin_amdgcn_mfma_f32_16x16x32_bf16(a, xs1.v, acc1[kk], 0, 0, 0);
            acc2[kk] = __builtin_amdgcn_mfma_f32_16x16x32_bf16(a, xs2.v, acc2[kk], 0, 0, 0);
        }
    }
#pragma unroll
    for (int kk = 0; kk < 4; ++kk) {
        const int k = w * 4 + kk;
        *(floatx4*)(sacc_p + (((size_t)jt * KK + k) * BB + b1) * ZZ + g * 4) = acc1[kk];
        *(floatx4*)(sacc_p + (((size_t)jt * KK + k) * BB + b2) * ZZ + g * 4) = acc2[kk];
    }
}

// ---- Pass D: 144-way reduce + squash. 4-way jt-split + shfl combine ----
extern "C" __global__ __launch_bounds__(256)
void kD(const float* __restrict__ sacc_p, float* __restrict__ out) {
    int p  = blockIdx.x * 256 + threadIdx.x;   // [0, KK*BB*16)
    int r  = p & 3;
    int q  = (p >> 2) & 3;
    int kb = p >> 4;
    int k  = kb >> 7;
    int b  = kb & 127;

    floatx4 v = (floatx4){0.f, 0.f, 0.f, 0.f};
#pragma unroll 6
    for (int jt = r * 36; jt < r * 36 + 36; ++jt)
        v += *(const floatx4*)(sacc_p + (((size_t)jt * KK + k) * BB + b) * ZZ + q * 4);

#pragma unroll
    for (int c = 0; c < 4; ++c) {
        v[c] += __shfl_xor(v[c], 1);
        v[c] += __shfl_xor(v[c], 2);
    }

    float nsq = v[0] * v[0];
    nsq = fmaf(v[1], v[1], nsq);
    nsq = fmaf(v[2], v[2], nsq);
    nsq = fmaf(v[3], v[3], nsq);
    nsq += __shfl_xor(nsq, 4);
    nsq += __shfl_xor(nsq, 8);

    float nr = sqrtf(nsq);
    float scale = (1.f - 1.f / (__expf(nr) + 1e-20f)) / (nr + 1e-20f);
    if (r == 0) {
        floatx4 o = v * scale;
        *(floatx4*)(out + ((size_t)b * KK + k) * ZZ + q * 4) = o;
    }
}

extern "C" void kernel_launch(void* const* d_in, const int* in_sizes, int n_in,
                              void* d_out, int out_size, void* d_ws, size_t ws_size,
                              hipStream_t stream) {
    const float* x    = (const float*)d_in[0];
    const float* W    = (const float*)d_in[1];
    const float* bias = (const float*)d_in[2];
    float*       out  = (float*)d_out;

    float* ws     = (float*)d_ws;
    float* usum   = ws;
    float* usum_p = usum + N_USUM;
    float* sacc_p = usum_p + N_USUMP;
    __hip_bfloat16* xbf = (__hip_bfloat16*)(sacc_p + N_SACCP);
    __hip_bfloat16* Wt  = xbf + (size_t)JJ * BB * II;

    // No memset: every workspace word is written before it is read.

    kP<<<KX_BLOCKS + KW_BLOCKS, 256, 0, stream>>>(x, W, xbf, Wt);
    kA<<<dim3(8, 4, NJG), 256, 0, stream>>>(xbf, Wt, usum_p);
    kR<<<(KK * BB * ZZ) / 256, 256, 0, stream>>>(usum_p, usum);
    kBC<<<dim3(NJT, 4), 512, 0, stream>>>(xbf, Wt, usum, bias, sacc_p);
    kD<<<(KK * BB * 16) / 256, 256, 0, stream>>>(sacc_p, out);
}

// Round 14
// 136.264 us; speedup vs baseline: 1.0752x; 1.0752x over previous
//
#include <hip/hip_runtime.h>
#include <hip/hip_bf16.h>
#include <math.h>

// Problem constants
#define BB 128
#define KK 32
#define JJ 1152
#define II 8
#define ZZ 16

#define NJG  12            // kA: 12 j-groups; block covers 24 quads (96 j)
#define NJT  288           // kBC: 288 j-tiles of 4 j

typedef __attribute__((ext_vector_type(8))) short short8;
typedef __attribute__((ext_vector_type(4))) float floatx4;

// Workspace float-word layout: [usum | usum_p | sacc_p | xbf | Wt]
#define N_USUM  (KK * BB * ZZ)                   // 65536
#define N_USUMP (NJG * KK * BB * ZZ)             // 786432
#define N_SACCP ((size_t)NJT * KK * BB * ZZ)     // 18874368 (75.5 MB)

#define KX_BLOCKS ((JJ * BB) / 256)              // 576
#define KW_BLOCKS ((KK * JJ * ZZ) / 256)         // 2304

__device__ __forceinline__ float bf2f(short h) {
    unsigned int w = ((unsigned int)(unsigned short)h) << 16;
    float f; __builtin_memcpy(&f, &w, 4);
    return f;
}

// ---- Merged prep: x -> xbf[j][b][i] bf16 ; W -> Wt[k][j][z][i] bf16 ----
extern "C" __global__ __launch_bounds__(256)
void kP(const float* __restrict__ x, const float* __restrict__ W,
        __hip_bfloat16* __restrict__ xbf, __hip_bfloat16* __restrict__ Wt) {
    if (blockIdx.x < KX_BLOCKS) {
        int idx = blockIdx.x * 256 + threadIdx.x;    // [0, J*B)
        int j_in = idx & 15;
        int rest = idx >> 4;
        int b    = rest & 127;
        int j    = (rest >> 7) * 16 + j_in;
        const float4* xp = (const float4*)(x + ((size_t)b * JJ + j) * II);
        float4 a = xp[0], c = xp[1];
        union { short8 v; __hip_bfloat16 h[8]; } u;
        u.h[0] = __float2bfloat16(a.x); u.h[1] = __float2bfloat16(a.y);
        u.h[2] = __float2bfloat16(a.z); u.h[3] = __float2bfloat16(a.w);
        u.h[4] = __float2bfloat16(c.x); u.h[5] = __float2bfloat16(c.y);
        u.h[6] = __float2bfloat16(c.z); u.h[7] = __float2bfloat16(c.w);
        *(short8*)(xbf + ((size_t)j * BB + b) * II) = u.v;
    } else {
        int idx = (blockIdx.x - KX_BLOCKS) * 256 + threadIdx.x;  // [0, K*J*16)
        int z    = idx & 15;
        int rest = idx >> 4;
        int j    = rest % JJ;
        int k    = rest / JJ;
        const float* src = W + (((size_t)k * JJ + j) * II) * ZZ + z;
        union { short8 v; __hip_bfloat16 h[8]; } u;
#pragma unroll
        for (int i = 0; i < II; ++i) u.h[i] = __float2bfloat16(src[i * ZZ]);
        *(short8*)(Wt + (((size_t)k * JJ + j) * ZZ + z) * II) = u.v;
    }
}

// ---- Pass A: usum_p[jg][k][b][z] partials; 4-wave blocks, LDS reduce ----
// grid (8 kt, 4 bt, NJG), block 256. Wave w covers quads jg*24 + w*6 .. +6.
extern "C" __global__ __launch_bounds__(256)
void kA(const __hip_bfloat16* __restrict__ xbf,
        const __hip_bfloat16* __restrict__ Wt, float* __restrict__ usum_p) {
    __shared__ float Ls[4][8][256];    // [w][slot=kk*2+half][lane*4+c] 32 KB
    const int kt = blockIdx.x;
    const int bt = blockIdx.y;
    const int jg = blockIdx.z;
    const int t  = threadIdx.x;
    const int w  = t >> 6;
    const int l  = t & 63;
    const int n  = l & 15;
    const int g  = l >> 4;
    const int b1 = bt * 32 + n;
    const int b2 = b1 + 16;
    const int q0 = jg * 24 + w * 6;

    short8 xv1[6], xv2[6];
#pragma unroll
    for (int q = 0; q < 6; ++q) {
        int j = (q0 + q) * 4 + g;
        xv1[q] = *(const short8*)(xbf + ((size_t)j * BB + b1) * II);
        xv2[q] = *(const short8*)(xbf + ((size_t)j * BB + b2) * II);
    }

    floatx4 acc1[4], acc2[4];
#pragma unroll
    for (int kk = 0; kk < 4; ++kk) {
        acc1[kk] = (floatx4){0.f, 0.f, 0.f, 0.f};
        acc2[kk] = (floatx4){0.f, 0.f, 0.f, 0.f};
    }

#pragma unroll
    for (int kk = 0; kk < 4; ++kk) {
        const int k = kt * 4 + kk;
#pragma unroll
        for (int q = 0; q < 6; ++q) {
            int j = (q0 + q) * 4 + g;
            short8 a = *(const short8*)(Wt + (((size_t)k * JJ + j) * ZZ + n) * II);
            acc1[kk] = __builtin_amdgcn_mfma_f32_16x16x32_bf16(a, xv1[q], acc1[kk], 0, 0, 0);
            acc2[kk] = __builtin_amdgcn_mfma_f32_16x16x32_bf16(a, xv2[q], acc2[kk], 0, 0, 0);
        }
    }
#pragma unroll
    for (int kk = 0; kk < 4; ++kk) {
        *(floatx4*)&Ls[w][kk * 2 + 0][l * 4] = acc1[kk];
        *(floatx4*)&Ls[w][kk * 2 + 1][l * 4] = acc2[kk];
    }
    __syncthreads();
    // Reduce across the 4 waves; 512 (slot,lane) pairs, 2 per thread.
#pragma unroll
    for (int pp = 0; pp < 2; ++pp) {
        int p  = t + pp * 256;
        int s  = p >> 6;
        int ll = p & 63;
        int nn = ll & 15, gg = ll >> 4;
        floatx4 v = *(const floatx4*)&Ls[0][s][ll * 4];
        v += *(const floatx4*)&Ls[1][s][ll * 4];
        v += *(const floatx4*)&Ls[2][s][ll * 4];
        v += *(const floatx4*)&Ls[3][s][ll * 4];
        int k = kt * 4 + (s >> 1);
        int b = bt * 32 + nn + 16 * (s & 1);
        *(floatx4*)(usum_p + (((size_t)jg * KK + k) * BB + b) * ZZ + gg * 4) = v;
    }
}

// ---- kR: usum = sum_jg usum_p. 4-way split + shfl combine ----
extern "C" __global__ __launch_bounds__(256)
void kR(const float* __restrict__ usum_p, float* __restrict__ usum) {
    int p   = blockIdx.x * 256 + threadIdx.x;    // [0, 65536)
    int r   = p & 3;
    int idx = p >> 2;                            // float4 index [0,16384)
    floatx4 s = (floatx4){0.f, 0.f, 0.f, 0.f};
#pragma unroll
    for (int jg = r * 3; jg < r * 3 + 3; ++jg)
        s += *(const floatx4*)(usum_p + (size_t)jg * N_USUM + (size_t)idx * 4);
#pragma unroll
    for (int c = 0; c < 4; ++c) {
        s[c] += __shfl_xor(s[c], 1);
        s[c] += __shfl_xor(s[c], 2);
    }
    if (r == 0) *(floatx4*)(usum + (size_t)idx * 4) = s;
}

// ---- Fused B+C over (4-j, 32-b) tile; 4 waves x 8 k each ----
// grid (NJT=288, 4 bt), block 256 -> 1152 blocks (~4.5/CU).
extern "C" __global__ __launch_bounds__(256)
void kBC(const __hip_bfloat16* __restrict__ xbf,
         const __hip_bfloat16* __restrict__ Wt,
         const float* __restrict__ usum, const float* __restrict__ bias,
         float* __restrict__ sacc_p) {
    __shared__ float eS[KK * 4 * 32];   // 16 KB: e[k][jl][col]
    __shared__ float Sw[4 * 4 * 32];    // 2 KB per-wave S partials
    __shared__ float rS[4 * 32];        // 512 B: 1/S[jl][col]

    const int jt = blockIdx.x;          // 0..287
    const int bt = blockIdx.y;          // 0..3
    const int t  = threadIdx.x;
    const int w  = t >> 6;              // 0..3 -> k-range w*8..w*8+7
    const int l  = t & 63;
    const int n  = l & 15;
    const int g  = l >> 4;
    const int b1 = bt * 32 + n;
    const int b2 = b1 + 16;
    const int j0 = jt * 4;

    short8 xv1[4], xv2[4];
#pragma unroll
    for (int jl = 0; jl < 4; ++jl) {
        xv1[jl] = *(const short8*)(xbf + ((size_t)(j0 + jl) * BB + b1) * II);
        xv2[jl] = *(const short8*)(xbf + ((size_t)(j0 + jl) * BB + b2) * II);
    }

    // ---- Phase 1: e + per-wave S ----
    float Sacc1[4], Sacc2[4];
#pragma unroll
    for (int jl = 0; jl < 4; ++jl) { Sacc1[jl] = 0.f; Sacc2[jl] = 0.f; }

#pragma unroll 2
    for (int kk = 0; kk < 8; ++kk) {
        const int k = w * 8 + kk;
        floatx4 us1 = *(const floatx4*)(usum + ((size_t)k * BB + b1) * ZZ + g * 4);
        floatx4 us2 = *(const floatx4*)(usum + ((size_t)k * BB + b2) * ZZ + g * 4);
#pragma unroll
        for (int jl = 0; jl < 4; ++jl) {
            short8 a = *(const short8*)(Wt + (((size_t)k * JJ + j0 + jl) * ZZ + n) * II);
            floatx4 c0 = {0.f, 0.f, 0.f, 0.f};
            floatx4 u1 = __builtin_amdgcn_mfma_f32_16x16x32_bf16(a, xv1[jl], c0, 0, 0, 0);
            floatx4 u2 = __builtin_amdgcn_mfma_f32_16x16x32_bf16(a, xv2[jl], c0, 0, 0, 0);
            float dp1 = u1[0] * us1[0];
            dp1 = fmaf(u1[1], us1[1], dp1);
            dp1 = fmaf(u1[2], us1[2], dp1);
            dp1 = fmaf(u1[3], us1[3], dp1);
            float dp2 = u2[0] * us2[0];
            dp2 = fmaf(u2[1], us2[1], dp2);
            dp2 = fmaf(u2[2], us2[2], dp2);
            dp2 = fmaf(u2[3], us2[3], dp2);
            dp1 += __shfl_xor(dp1, 16);
            dp1 += __shfl_xor(dp1, 32);
            dp2 += __shfl_xor(dp2, 16);
            dp2 += __shfl_xor(dp2, 32);
            float e1 = __expf(dp1 * 0.0625f);   // 0.25 softmax * 0.25 K-dup
            float e2 = __expf(dp2 * 0.0625f);
            Sacc1[jl] += e1;
            Sacc2[jl] += e2;
            if (g == 0) {
                eS[(k * 4 + jl) * 32 + n]      = e1;
                eS[(k * 4 + jl) * 32 + n + 16] = e2;
            }
        }
    }
    if (g == 0) {
#pragma unroll
        for (int jl = 0; jl < 4; ++jl) {
            Sw[(w * 4 + jl) * 32 + n]      = Sacc1[jl];
            Sw[(w * 4 + jl) * 32 + n + 16] = Sacc2[jl];
        }
    }
    __syncthreads();
    if (t < 128) {
        int jl = t >> 5, col = t & 31;
        float s = Sw[(0 * 4 + jl) * 32 + col] + Sw[(1 * 4 + jl) * 32 + col]
                + Sw[(2 * 4 + jl) * 32 + col] + Sw[(3 * 4 + jl) * 32 + col];
        rS[jl * 32 + col] = __builtin_amdgcn_rcpf(s);
    }
    __syncthreads();

    // ---- Phase 2: sacc, c folded into B-operand; j = j0 + g per lane ----
    float xf1[8], xf2[8];
    {
        union { short8 v; short s[8]; } xr1, xr2;
        int j = j0 + g;
        xr1.v = *(const short8*)(xbf + ((size_t)j * BB + b1) * II);
        xr2.v = *(const short8*)(xbf + ((size_t)j * BB + b2) * II);
#pragma unroll
        for (int i = 0; i < II; ++i) {
            xf1[i] = bf2f(xr1.s[i]);
            xf2[i] = bf2f(xr2.s[i]);
        }
    }

#pragma unroll 2
    for (int kk = 0; kk < 8; ++kk) {
        const int k = w * 8 + kk;
        float bj = bias[(size_t)k * JJ + j0 + g];
        float c1 = fmaf(eS[(k * 4 + g) * 32 + n],      rS[g * 32 + n],      bj);
        float c2 = fmaf(eS[(k * 4 + g) * 32 + n + 16], rS[g * 32 + n + 16], bj);
        union { short8 v; short s[8]; } xs1, xs2;
#pragma unroll
        for (int i = 0; i < II; ++i) {
            __hip_bfloat16 h1 = __float2bfloat16(xf1[i] * c1);
            __hip_bfloat16 h2 = __float2bfloat16(xf2[i] * c2);
            __builtin_memcpy(&xs1.s[i], &h1, 2);
            __builtin_memcpy(&xs2.s[i], &h2, 2);
        }
        short8 a = *(const short8*)(Wt + (((size_t)k * JJ + j0 + g) * ZZ + n) * II);
        floatx4 c0 = {0.f, 0.f, 0.f, 0.f};
        floatx4 a1 = __builtin_amdgcn_mfma_f32_16x16x32_bf16(a, xs1.v, c0, 0, 0, 0);
        floatx4 a2 = __builtin_amdgcn_mfma_f32_16x16x32_bf16(a, xs2.v, c0, 0, 0, 0);
        *(floatx4*)(sacc_p + (((size_t)jt * KK + k) * BB + b1) * ZZ + g * 4) = a1;
        *(floatx4*)(sacc_p + (((size_t)jt * KK + k) * BB + b2) * ZZ + g * 4) = a2;
    }
}

// ---- Pass D: 288-way reduce + squash. 4-way jt-split + shfl combine ----
extern "C" __global__ __launch_bounds__(256)
void kD(const float* __restrict__ sacc_p, float* __restrict__ out) {
    int p  = blockIdx.x * 256 + threadIdx.x;   // [0, KK*BB*16)
    int r  = p & 3;
    int q  = (p >> 2) & 3;
    int kb = p >> 4;
    int k  = kb >> 7;
    int b  = kb & 127;

    floatx4 v = (floatx4){0.f, 0.f, 0.f, 0.f};
#pragma unroll 8
    for (int jt = r * 72; jt < r * 72 + 72; ++jt)
        v += *(const floatx4*)(sacc_p + (((size_t)jt * KK + k) * BB + b) * ZZ + q * 4);

#pragma unroll
    for (int c = 0; c < 4; ++c) {
        v[c] += __shfl_xor(v[c], 1);
        v[c] += __shfl_xor(v[c], 2);
    }

    float nsq = v[0] * v[0];
    nsq = fmaf(v[1], v[1], nsq);
    nsq = fmaf(v[2], v[2], nsq);
    nsq = fmaf(v[3], v[3], nsq);
    nsq += __shfl_xor(nsq, 4);
    nsq += __shfl_xor(nsq, 8);

    float nr = sqrtf(nsq);
    float scale = (1.f - 1.f / (__expf(nr) + 1e-20f)) / (nr + 1e-20f);
    if (r == 0) {
        floatx4 o = v * scale;
        *(floatx4*)(out + ((size_t)b * KK + k) * ZZ + q * 4) = o;
    }
}

extern "C" void kernel_launch(void* const* d_in, const int* in_sizes, int n_in,
                              void* d_out, int out_size, void* d_ws, size_t ws_size,
                              hipStream_t stream) {
    const float* x    = (const float*)d_in[0];
    const float* W    = (const float*)d_in[1];
    const float* bias = (const float*)d_in[2];
    float*       out  = (float*)d_out;

    float* ws     = (float*)d_ws;
    float* usum   = ws;
    float* usum_p = usum + N_USUM;
    float* sacc_p = usum_p + N_USUMP;
    __hip_bfloat16* xbf = (__hip_bfloat16*)(sacc_p + N_SACCP);
    __hip_bfloat16* Wt  = xbf + (size_t)JJ * BB * II;

    // No memset: every workspace word is written before it is read.

    kP<<<KX_BLOCKS + KW_BLOCKS, 256, 0, stream>>>(x, W, xbf, Wt);
    kA<<<dim3(8, 4, NJG), 256, 0, stream>>>(xbf, Wt, usum_p);
    kR<<<(KK * BB * ZZ) / 256, 256, 0, stream>>>(usum_p, usum);
    kBC<<<dim3(NJT, 4), 256, 0, stream>>>(xbf, Wt, usum, bias, sacc_p);
    kD<<<(KK * BB * 16) / 256, 256, 0, stream>>>(sacc_p, out);
}

// Round 15
// 121.770 us; speedup vs baseline: 1.2032x; 1.1190x over previous
//
#include <hip/hip_runtime.h>
#include <hip/hip_bf16.h>
#include <math.h>

// Problem constants
#define BB 128
#define KK 32
#define JJ 1152
#define II 8
#define ZZ 16

#define NJG  12            // kA: 12 j-groups; block covers 24 quads (96 j)
#define NJT  144           // kBC: 144 j-tiles of 8 j

typedef __attribute__((ext_vector_type(8))) short short8;
typedef __attribute__((ext_vector_type(4))) short short4v;
typedef __attribute__((ext_vector_type(4))) float floatx4;

// Workspace float-word layout: [usum | usum_p | sacc_p(bf16) | xbf | Wt]
#define N_USUM  (KK * BB * ZZ)                   // 65536 floats
#define N_USUMP (NJG * KK * BB * ZZ)             // 786432 floats
#define N_SACCP ((size_t)NJT * KK * BB * ZZ)     // 9437184 bf16 elems (18.9 MB)

#define KX_BLOCKS ((JJ * BB) / 256)              // 576
#define KW_BLOCKS ((KK * JJ * ZZ) / 256)         // 2304

// sacc_p offset (bf16 elems): [jt][k][zq(4)][b(128)][z4(4)]
#define SOFF(jt, k, q, b) (((((size_t)(jt) * KK + (k)) * 4 + (q)) * BB + (b)) * 4)

__device__ __forceinline__ float bf2f(short h) {
    unsigned int w = ((unsigned int)(unsigned short)h) << 16;
    float f; __builtin_memcpy(&f, &w, 4);
    return f;
}

// ---- Merged prep: x -> xbf[j][b][i] bf16 ; W -> Wt[k][j][z][i] bf16 ----
extern "C" __global__ __launch_bounds__(256)
void kP(const float* __restrict__ x, const float* __restrict__ W,
        __hip_bfloat16* __restrict__ xbf, __hip_bfloat16* __restrict__ Wt) {
    if (blockIdx.x < KX_BLOCKS) {
        int idx = blockIdx.x * 256 + threadIdx.x;    // [0, J*B)
        int j_in = idx & 15;
        int rest = idx >> 4;
        int b    = rest & 127;
        int j    = (rest >> 7) * 16 + j_in;
        const float4* xp = (const float4*)(x + ((size_t)b * JJ + j) * II);
        float4 a = xp[0], c = xp[1];
        union { short8 v; __hip_bfloat16 h[8]; } u;
        u.h[0] = __float2bfloat16(a.x); u.h[1] = __float2bfloat16(a.y);
        u.h[2] = __float2bfloat16(a.z); u.h[3] = __float2bfloat16(a.w);
        u.h[4] = __float2bfloat16(c.x); u.h[5] = __float2bfloat16(c.y);
        u.h[6] = __float2bfloat16(c.z); u.h[7] = __float2bfloat16(c.w);
        *(short8*)(xbf + ((size_t)j * BB + b) * II) = u.v;
    } else {
        int idx = (blockIdx.x - KX_BLOCKS) * 256 + threadIdx.x;  // [0, K*J*16)
        int z    = idx & 15;
        int rest = idx >> 4;
        int j    = rest % JJ;
        int k    = rest / JJ;
        const float* src = W + (((size_t)k * JJ + j) * II) * ZZ + z;
        union { short8 v; __hip_bfloat16 h[8]; } u;
#pragma unroll
        for (int i = 0; i < II; ++i) u.h[i] = __float2bfloat16(src[i * ZZ]);
        *(short8*)(Wt + (((size_t)k * JJ + j) * ZZ + z) * II) = u.v;
    }
}

// ---- Pass A: usum_p[jg][k][b][z] partials; 4-wave blocks, LDS reduce ----
extern "C" __global__ __launch_bounds__(256)
void kA(const __hip_bfloat16* __restrict__ xbf,
        const __hip_bfloat16* __restrict__ Wt, float* __restrict__ usum_p) {
    __shared__ float Ls[4][8][256];    // [w][slot=kk*2+half][lane*4+c] 32 KB
    const int kt = blockIdx.x;
    const int bt = blockIdx.y;
    const int jg = blockIdx.z;
    const int t  = threadIdx.x;
    const int w  = t >> 6;
    const int l  = t & 63;
    const int n  = l & 15;
    const int g  = l >> 4;
    const int b1 = bt * 32 + n;
    const int b2 = b1 + 16;
    const int q0 = jg * 24 + w * 6;

    short8 xv1[6], xv2[6];
#pragma unroll
    for (int q = 0; q < 6; ++q) {
        int j = (q0 + q) * 4 + g;
        xv1[q] = *(const short8*)(xbf + ((size_t)j * BB + b1) * II);
        xv2[q] = *(const short8*)(xbf + ((size_t)j * BB + b2) * II);
    }

    floatx4 acc1[4], acc2[4];
#pragma unroll
    for (int kk = 0; kk < 4; ++kk) {
        acc1[kk] = (floatx4){0.f, 0.f, 0.f, 0.f};
        acc2[kk] = (floatx4){0.f, 0.f, 0.f, 0.f};
    }

#pragma unroll
    for (int kk = 0; kk < 4; ++kk) {
        const int k = kt * 4 + kk;
#pragma unroll
        for (int q = 0; q < 6; ++q) {
            int j = (q0 + q) * 4 + g;
            short8 a = *(const short8*)(Wt + (((size_t)k * JJ + j) * ZZ + n) * II);
            acc1[kk] = __builtin_amdgcn_mfma_f32_16x16x32_bf16(a, xv1[q], acc1[kk], 0, 0, 0);
            acc2[kk] = __builtin_amdgcn_mfma_f32_16x16x32_bf16(a, xv2[q], acc2[kk], 0, 0, 0);
        }
    }
#pragma unroll
    for (int kk = 0; kk < 4; ++kk) {
        *(floatx4*)&Ls[w][kk * 2 + 0][l * 4] = acc1[kk];
        *(floatx4*)&Ls[w][kk * 2 + 1][l * 4] = acc2[kk];
    }
    __syncthreads();
#pragma unroll
    for (int pp = 0; pp < 2; ++pp) {
        int p  = t + pp * 256;
        int s  = p >> 6;
        int ll = p & 63;
        int nn = ll & 15, gg = ll >> 4;
        floatx4 v = *(const floatx4*)&Ls[0][s][ll * 4];
        v += *(const floatx4*)&Ls[1][s][ll * 4];
        v += *(const floatx4*)&Ls[2][s][ll * 4];
        v += *(const floatx4*)&Ls[3][s][ll * 4];
        int k = kt * 4 + (s >> 1);
        int b = bt * 32 + nn + 16 * (s & 1);
        *(floatx4*)(usum_p + (((size_t)jg * KK + k) * BB + b) * ZZ + gg * 4) = v;
    }
}

// ---- kR: usum = sum_jg usum_p. 4-way split + shfl combine ----
extern "C" __global__ __launch_bounds__(256)
void kR(const float* __restrict__ usum_p, float* __restrict__ usum) {
    int p   = blockIdx.x * 256 + threadIdx.x;    // [0, 65536)
    int r   = p & 3;
    int idx = p >> 2;                            // float4 index [0,16384)
    floatx4 s = (floatx4){0.f, 0.f, 0.f, 0.f};
#pragma unroll
    for (int jg = r * 3; jg < r * 3 + 3; ++jg)
        s += *(const floatx4*)(usum_p + (size_t)jg * N_USUM + (size_t)idx * 4);
#pragma unroll
    for (int c = 0; c < 4; ++c) {
        s[c] += __shfl_xor(s[c], 1);
        s[c] += __shfl_xor(s[c], 2);
    }
    if (r == 0) *(floatx4*)(usum + (size_t)idx * 4) = s;
}

// ---- Fused B+C over (8-j, 32-b) tile; 4 waves x 8 k; batched phase-1 ILP ----
// grid (NJT=144, 4 bt) = 576 blocks.
extern "C" __global__ __launch_bounds__(256)
void kBC(const __hip_bfloat16* __restrict__ xbf,
         const __hip_bfloat16* __restrict__ Wt,
         const float* __restrict__ usum, const float* __restrict__ bias,
         __hip_bfloat16* __restrict__ sacc_p) {
    __shared__ float eS[KK * 8 * 33];   // padded rows (33) -> conflict-free g-reads
    __shared__ float Sw[4 * 8 * 32];
    __shared__ float rS[8 * 32];

    const int jt = blockIdx.x;          // 0..143
    const int bt = blockIdx.y;          // 0..3
    const int t  = threadIdx.x;
    const int w  = t >> 6;              // 0..3 -> k-range w*8..w*8+7
    const int l  = t & 63;
    const int n  = l & 15;
    const int g  = l >> 4;
    const int b1 = bt * 32 + n;
    const int b2 = b1 + 16;
    const int j0 = jt * 8;

    short8 xv1[8], xv2[8];
#pragma unroll
    for (int jl = 0; jl < 8; ++jl) {
        xv1[jl] = *(const short8*)(xbf + ((size_t)(j0 + jl) * BB + b1) * II);
        xv2[jl] = *(const short8*)(xbf + ((size_t)(j0 + jl) * BB + b2) * II);
    }

    // ---- Phase 1: e + per-wave S, batched for ILP ----
    float Sacc1[8], Sacc2[8];
#pragma unroll
    for (int jl = 0; jl < 8; ++jl) { Sacc1[jl] = 0.f; Sacc2[jl] = 0.f; }

    for (int kk = 0; kk < 8; ++kk) {
        const int k = w * 8 + kk;
        floatx4 us1 = *(const floatx4*)(usum + ((size_t)k * BB + b1) * ZZ + g * 4);
        floatx4 us2 = *(const floatx4*)(usum + ((size_t)k * BB + b2) * ZZ + g * 4);
#pragma unroll
        for (int h = 0; h < 2; ++h) {
            // batch of 4 jl: all MFMAs, then dots, then shfls, then exps
            floatx4 u1[4], u2[4];
#pragma unroll
            for (int j4 = 0; j4 < 4; ++j4) {
                short8 a = *(const short8*)(Wt +
                    (((size_t)k * JJ + j0 + h * 4 + j4) * ZZ + n) * II);
                floatx4 c0 = {0.f, 0.f, 0.f, 0.f};
                u1[j4] = __builtin_amdgcn_mfma_f32_16x16x32_bf16(a, xv1[h * 4 + j4], c0, 0, 0, 0);
                u2[j4] = __builtin_amdgcn_mfma_f32_16x16x32_bf16(a, xv2[h * 4 + j4], c0, 0, 0, 0);
            }
            float dp1[4], dp2[4];
#pragma unroll
            for (int j4 = 0; j4 < 4; ++j4) {
                float d1 = u1[j4][0] * us1[0];
                d1 = fmaf(u1[j4][1], us1[1], d1);
                d1 = fmaf(u1[j4][2], us1[2], d1);
                d1 = fmaf(u1[j4][3], us1[3], d1);
                float d2 = u2[j4][0] * us2[0];
                d2 = fmaf(u2[j4][1], us2[1], d2);
                d2 = fmaf(u2[j4][2], us2[2], d2);
                d2 = fmaf(u2[j4][3], us2[3], d2);
                dp1[j4] = d1; dp2[j4] = d2;
            }
            float t1[4], t2[4];
#pragma unroll
            for (int j4 = 0; j4 < 4; ++j4) {
                t1[j4] = __shfl_xor(dp1[j4], 16);
                t2[j4] = __shfl_xor(dp2[j4], 16);
            }
#pragma unroll
            for (int j4 = 0; j4 < 4; ++j4) { dp1[j4] += t1[j4]; dp2[j4] += t2[j4]; }
#pragma unroll
            for (int j4 = 0; j4 < 4; ++j4) {
                t1[j4] = __shfl_xor(dp1[j4], 32);
                t2[j4] = __shfl_xor(dp2[j4], 32);
            }
#pragma unroll
            for (int j4 = 0; j4 < 4; ++j4) { dp1[j4] += t1[j4]; dp2[j4] += t2[j4]; }
#pragma unroll
            for (int j4 = 0; j4 < 4; ++j4) {
                float e1 = __expf(dp1[j4] * 0.0625f);   // 0.25 softmax * 0.25 K-dup
                float e2 = __expf(dp2[j4] * 0.0625f);
                Sacc1[h * 4 + j4] += e1;
                Sacc2[h * 4 + j4] += e2;
                if (g == 0) {
                    eS[(k * 8 + h * 4 + j4) * 33 + n]      = e1;
                    eS[(k * 8 + h * 4 + j4) * 33 + n + 16] = e2;
                }
            }
        }
    }
    if (g == 0) {
#pragma unroll
        for (int jl = 0; jl < 8; ++jl) {
            Sw[(w * 8 + jl) * 32 + n]      = Sacc1[jl];
            Sw[(w * 8 + jl) * 32 + n + 16] = Sacc2[jl];
        }
    }
    __syncthreads();
    {
        int jl = t >> 5, col = t & 31;   // 256 threads exactly
        float s = Sw[(0 * 8 + jl) * 32 + col] + Sw[(1 * 8 + jl) * 32 + col]
                + Sw[(2 * 8 + jl) * 32 + col] + Sw[(3 * 8 + jl) * 32 + col];
        rS[jl * 32 + col] = __builtin_amdgcn_rcpf(s);
    }
    __syncthreads();

    // ---- Phase 2: sacc partial, c folded into B-operand; bf16 output ----
    float xf1[2][8], xf2[2][8];
#pragma unroll
    for (int quad = 0; quad < 2; ++quad) {
        union { short8 v; short s[8]; } xr1, xr2;
        int j = j0 + quad * 4 + g;
        xr1.v = *(const short8*)(xbf + ((size_t)j * BB + b1) * II);
        xr2.v = *(const short8*)(xbf + ((size_t)j * BB + b2) * II);
#pragma unroll
        for (int i = 0; i < II; ++i) {
            xf1[quad][i] = bf2f(xr1.s[i]);
            xf2[quad][i] = bf2f(xr2.s[i]);
        }
    }

    for (int kk = 0; kk < 8; ++kk) {
        const int k = w * 8 + kk;
        floatx4 acc1 = {0.f, 0.f, 0.f, 0.f};
        floatx4 acc2 = {0.f, 0.f, 0.f, 0.f};
#pragma unroll
        for (int quad = 0; quad < 2; ++quad) {
            const int jl = quad * 4 + g;
            const int j  = j0 + jl;
            float bj = bias[(size_t)k * JJ + j];
            float c1 = fmaf(eS[(k * 8 + jl) * 33 + n],      rS[jl * 32 + n],      bj);
            float c2 = fmaf(eS[(k * 8 + jl) * 33 + n + 16], rS[jl * 32 + n + 16], bj);
            union { short8 v; short s[8]; } xs1, xs2;
#pragma unroll
            for (int i = 0; i < II; ++i) {
                __hip_bfloat16 h1 = __float2bfloat16(xf1[quad][i] * c1);
                __hip_bfloat16 h2 = __float2bfloat16(xf2[quad][i] * c2);
                __builtin_memcpy(&xs1.s[i], &h1, 2);
                __builtin_memcpy(&xs2.s[i], &h2, 2);
            }
            short8 a = *(const short8*)(Wt + (((size_t)k * JJ + j) * ZZ + n) * II);
            acc1 = __builtin_amdgcn_mfma_f32_16x16x32_bf16(a, xs1.v, acc1, 0, 0, 0);
            acc2 = __builtin_amdgcn_mfma_f32_16x16x32_bf16(a, xs2.v, acc2, 0, 0, 0);
        }
        union { short4v v; short s[4]; } o1, o2;
#pragma unroll
        for (int r = 0; r < 4; ++r) {
            __hip_bfloat16 h1 = __float2bfloat16(acc1[r]);
            __hip_bfloat16 h2 = __float2bfloat16(acc2[r]);
            __builtin_memcpy(&o1.s[r], &h1, 2);
            __builtin_memcpy(&o2.s[r], &h2, 2);
        }
        *(short4v*)(sacc_p + SOFF(jt, k, g, b1)) = o1.v;
        *(short4v*)(sacc_p + SOFF(jt, k, g, b2)) = o2.v;
    }
}

// ---- Pass D: 144-way bf16 reduce + squash. 4-way jt-split + shfl combine ----
extern "C" __global__ __launch_bounds__(256)
void kD(const __hip_bfloat16* __restrict__ sacc_p, float* __restrict__ out) {
    int p  = blockIdx.x * 256 + threadIdx.x;   // [0, KK*BB*16)
    int r  = p & 3;
    int q  = (p >> 2) & 3;
    int kb = p >> 4;
    int k  = kb >> 7;
    int b  = kb & 127;

    floatx4 v = (floatx4){0.f, 0.f, 0.f, 0.f};
#pragma unroll 6
    for (int jt = r * 36; jt < r * 36 + 36; ++jt) {
        union { short4v sv; short s[4]; } u;
        u.sv = *(const short4v*)(sacc_p + SOFF(jt, k, q, b));
        v[0] += bf2f(u.s[0]);
        v[1] += bf2f(u.s[1]);
        v[2] += bf2f(u.s[2]);
        v[3] += bf2f(u.s[3]);
    }

#pragma unroll
    for (int c = 0; c < 4; ++c) {
        v[c] += __shfl_xor(v[c], 1);
        v[c] += __shfl_xor(v[c], 2);
    }

    float nsq = v[0] * v[0];
    nsq = fmaf(v[1], v[1], nsq);
    nsq = fmaf(v[2], v[2], nsq);
    nsq = fmaf(v[3], v[3], nsq);
    nsq += __shfl_xor(nsq, 4);
    nsq += __shfl_xor(nsq, 8);

    float nr = sqrtf(nsq);
    float scale = (1.f - 1.f / (__expf(nr) + 1e-20f)) / (nr + 1e-20f);
    if (r == 0) {
        floatx4 o = v * scale;
        *(floatx4*)(out + ((size_t)b * KK + k) * ZZ + q * 4) = o;
    }
}

extern "C" void kernel_launch(void* const* d_in, const int* in_sizes, int n_in,
                              void* d_out, int out_size, void* d_ws, size_t ws_size,
                              hipStream_t stream) {
    const float* x    = (const float*)d_in[0];
    const float* W    = (const float*)d_in[1];
    const float* bias = (const float*)d_in[2];
    float*       out  = (float*)d_out;

    float* ws     = (float*)d_ws;
    float* usum   = ws;
    float* usum_p = usum + N_USUM;
    __hip_bfloat16* sacc_p = (__hip_bfloat16*)(usum_p + N_USUMP);
    __hip_bfloat16* xbf    = sacc_p + N_SACCP;
    __hip_bfloat16* Wt     = xbf + (size_t)JJ * BB * II;

    // No memset: every workspace word is written before it is read.

    kP<<<KX_BLOCKS + KW_BLOCKS, 256, 0, stream>>>(x, W, xbf, Wt);
    kA<<<dim3(8, 4, NJG), 256, 0, stream>>>(xbf, Wt, usum_p);
    kR<<<(KK * BB * ZZ) / 256, 256, 0, stream>>>(usum_p, usum);
    kBC<<<dim3(NJT, 4), 256, 0, stream>>>(xbf, Wt, usum, bias, sacc_p);
    kD<<<(KK * BB * 16) / 256, 256, 0, stream>>>(sacc_p, out);
}

// Round 16
// 112.005 us; speedup vs baseline: 1.3081x; 1.0872x over previous
//
#include <hip/hip_runtime.h>
#include <hip/hip_bf16.h>
#include <math.h>

// Problem constants
#define BB 128
#define KK 32
#define JJ 1152
#define II 8
#define ZZ 16

#define NJG  12            // kA: 12 j-groups; block covers 24 quads (96 j)
#define NJT  144           // kBC: 144 j-tiles of 8 j

typedef __attribute__((ext_vector_type(8))) short short8;
typedef __attribute__((ext_vector_type(4))) short short4v;
typedef __attribute__((ext_vector_type(4))) float floatx4;

// Workspace float-word layout: [usum | usum_p | sacc_p(bf16) | xbf | Wt]
#define N_USUM  (KK * BB * ZZ)                   // 65536 floats
#define N_USUMP (NJG * KK * BB * ZZ)             // 786432 floats
#define N_SACCP ((size_t)NJT * KK * BB * ZZ)     // 9437184 bf16 elems (18.9 MB)

#define KX_BLOCKS ((JJ * BB) / 256)              // 576
#define KW_BLOCKS ((KK * JJ * ZZ) / 256)         // 2304

// sacc_p offset (bf16 elems): [jt][k][zq(4)][b(128)][z4(4)]
#define SOFF(jt, k, q, b) (((((size_t)(jt) * KK + (k)) * 4 + (q)) * BB + (b)) * 4)

__device__ __forceinline__ float bf2f(short h) {
    unsigned int w = ((unsigned int)(unsigned short)h) << 16;
    float f; __builtin_memcpy(&f, &w, 4);
    return f;
}

// ---- Merged prep: x -> xbf[j][b][i] bf16 ; W -> Wt[k][j][z][i] bf16 ----
extern "C" __global__ __launch_bounds__(256)
void kP(const float* __restrict__ x, const float* __restrict__ W,
        __hip_bfloat16* __restrict__ xbf, __hip_bfloat16* __restrict__ Wt) {
    if (blockIdx.x < KX_BLOCKS) {
        int idx = blockIdx.x * 256 + threadIdx.x;    // [0, J*B)
        int j_in = idx & 15;
        int rest = idx >> 4;
        int b    = rest & 127;
        int j    = (rest >> 7) * 16 + j_in;
        const float4* xp = (const float4*)(x + ((size_t)b * JJ + j) * II);
        float4 a = xp[0], c = xp[1];
        union { short8 v; __hip_bfloat16 h[8]; } u;
        u.h[0] = __float2bfloat16(a.x); u.h[1] = __float2bfloat16(a.y);
        u.h[2] = __float2bfloat16(a.z); u.h[3] = __float2bfloat16(a.w);
        u.h[4] = __float2bfloat16(c.x); u.h[5] = __float2bfloat16(c.y);
        u.h[6] = __float2bfloat16(c.z); u.h[7] = __float2bfloat16(c.w);
        *(short8*)(xbf + ((size_t)j * BB + b) * II) = u.v;
    } else {
        int idx = (blockIdx.x - KX_BLOCKS) * 256 + threadIdx.x;  // [0, K*J*16)
        int z    = idx & 15;
        int rest = idx >> 4;
        int j    = rest % JJ;
        int k    = rest / JJ;
        const float* src = W + (((size_t)k * JJ + j) * II) * ZZ + z;
        union { short8 v; __hip_bfloat16 h[8]; } u;
#pragma unroll
        for (int i = 0; i < II; ++i) u.h[i] = __float2bfloat16(src[i * ZZ]);
        *(short8*)(Wt + (((size_t)k * JJ + j) * ZZ + z) * II) = u.v;
    }
}

// ---- Pass A: usum_p[jg][k][b][z] partials; 16-b blocks, 4-wave LDS reduce ----
// grid (8 kt, 8 bt, NJG), block 256. Wave w covers quads jg*24 + w*6 .. +6.
extern "C" __global__ __launch_bounds__(256)
void kA(const __hip_bfloat16* __restrict__ xbf,
        const __hip_bfloat16* __restrict__ Wt, float* __restrict__ usum_p) {
    __shared__ float Ls[4][4][256];    // [w][kk][lane*4+c] 16 KB
    const int kt = blockIdx.x;
    const int bt = blockIdx.y;
    const int jg = blockIdx.z;
    const int t  = threadIdx.x;
    const int w  = t >> 6;
    const int l  = t & 63;
    const int n  = l & 15;
    const int g  = l >> 4;
    const int b  = bt * 16 + n;
    const int q0 = jg * 24 + w * 6;

    short8 xv[6];
#pragma unroll
    for (int q = 0; q < 6; ++q) {
        int j = (q0 + q) * 4 + g;
        xv[q] = *(const short8*)(xbf + ((size_t)j * BB + b) * II);
    }

    floatx4 acc[4];
#pragma unroll
    for (int kk = 0; kk < 4; ++kk) acc[kk] = (floatx4){0.f, 0.f, 0.f, 0.f};

#pragma unroll
    for (int kk = 0; kk < 4; ++kk) {
        const int k = kt * 4 + kk;
#pragma unroll
        for (int q = 0; q < 6; ++q) {
            int j = (q0 + q) * 4 + g;
            short8 a = *(const short8*)(Wt + (((size_t)k * JJ + j) * ZZ + n) * II);
            acc[kk] = __builtin_amdgcn_mfma_f32_16x16x32_bf16(a, xv[q], acc[kk], 0, 0, 0);
        }
    }
#pragma unroll
    for (int kk = 0; kk < 4; ++kk)
        *(floatx4*)&Ls[w][kk][l * 4] = acc[kk];
    __syncthreads();
    // Reduce across 4 waves: 256 (kk,lane) pairs, one per thread.
    {
        int kk = t >> 6;
        int ll = t & 63;
        int nn = ll & 15, gg = ll >> 4;
        floatx4 v = *(const floatx4*)&Ls[0][kk][ll * 4];
        v += *(const floatx4*)&Ls[1][kk][ll * 4];
        v += *(const floatx4*)&Ls[2][kk][ll * 4];
        v += *(const floatx4*)&Ls[3][kk][ll * 4];
        int k  = kt * 4 + kk;
        int bb = bt * 16 + nn;
        *(floatx4*)(usum_p + (((size_t)jg * KK + k) * BB + bb) * ZZ + gg * 4) = v;
    }
}

// ---- kR: usum = sum_jg usum_p. 4-way split + shfl combine ----
extern "C" __global__ __launch_bounds__(256)
void kR(const float* __restrict__ usum_p, float* __restrict__ usum) {
    int p   = blockIdx.x * 256 + threadIdx.x;    // [0, 65536)
    int r   = p & 3;
    int idx = p >> 2;                            // float4 index [0,16384)
    floatx4 s = (floatx4){0.f, 0.f, 0.f, 0.f};
#pragma unroll
    for (int jg = r * 3; jg < r * 3 + 3; ++jg)
        s += *(const floatx4*)(usum_p + (size_t)jg * N_USUM + (size_t)idx * 4);
#pragma unroll
    for (int c = 0; c < 4; ++c) {
        s[c] += __shfl_xor(s[c], 1);
        s[c] += __shfl_xor(s[c], 2);
    }
    if (r == 0) *(floatx4*)(usum + (size_t)idx * 4) = s;
}

// ---- Fused B+C over (8-j, 16-b) tile; 4 waves x 8 k; batched phase-1 ILP ----
// grid (NJT=144, 8 bt) = 1152 blocks (~4.5/CU, ~18 waves/CU).
extern "C" __global__ __launch_bounds__(256)
void kBC(const __hip_bfloat16* __restrict__ xbf,
         const __hip_bfloat16* __restrict__ Wt,
         const float* __restrict__ usum, const float* __restrict__ bias,
         __hip_bfloat16* __restrict__ sacc_p) {
    __shared__ float eS[KK * 8 * 17];   // 17.4 KB, padded rows -> <=2-way aliasing
    __shared__ float Sw[4 * 8 * 16];    // 2 KB per-wave S partials
    __shared__ float rS[8 * 16];        // 512 B: 1/S[jl][n]

    const int jt = blockIdx.x;          // 0..143
    const int bt = blockIdx.y;          // 0..7
    const int t  = threadIdx.x;
    const int w  = t >> 6;              // 0..3 -> k-range w*8..w*8+7
    const int l  = t & 63;
    const int n  = l & 15;
    const int g  = l >> 4;
    const int b  = bt * 16 + n;
    const int j0 = jt * 8;

    short8 xv[8];
#pragma unroll
    for (int jl = 0; jl < 8; ++jl)
        xv[jl] = *(const short8*)(xbf + ((size_t)(j0 + jl) * BB + b) * II);

    // ---- Phase 1: e + per-wave S, batched for ILP ----
    float Sacc[8];
#pragma unroll
    for (int jl = 0; jl < 8; ++jl) Sacc[jl] = 0.f;

    for (int kk = 0; kk < 8; ++kk) {
        const int k = w * 8 + kk;
        floatx4 us = *(const floatx4*)(usum + ((size_t)k * BB + b) * ZZ + g * 4);
#pragma unroll
        for (int h = 0; h < 2; ++h) {
            floatx4 u4[4];
#pragma unroll
            for (int j4 = 0; j4 < 4; ++j4) {
                short8 a = *(const short8*)(Wt +
                    (((size_t)k * JJ + j0 + h * 4 + j4) * ZZ + n) * II);
                floatx4 c0 = {0.f, 0.f, 0.f, 0.f};
                u4[j4] = __builtin_amdgcn_mfma_f32_16x16x32_bf16(a, xv[h * 4 + j4], c0, 0, 0, 0);
            }
            float dp[4];
#pragma unroll
            for (int j4 = 0; j4 < 4; ++j4) {
                float d = u4[j4][0] * us[0];
                d = fmaf(u4[j4][1], us[1], d);
                d = fmaf(u4[j4][2], us[2], d);
                d = fmaf(u4[j4][3], us[3], d);
                dp[j4] = d;
            }
            float tt[4];
#pragma unroll
            for (int j4 = 0; j4 < 4; ++j4) tt[j4] = __shfl_xor(dp[j4], 16);
#pragma unroll
            for (int j4 = 0; j4 < 4; ++j4) dp[j4] += tt[j4];
#pragma unroll
            for (int j4 = 0; j4 < 4; ++j4) tt[j4] = __shfl_xor(dp[j4], 32);
#pragma unroll
            for (int j4 = 0; j4 < 4; ++j4) dp[j4] += tt[j4];
#pragma unroll
            for (int j4 = 0; j4 < 4; ++j4) {
                float e = __expf(dp[j4] * 0.0625f);   // 0.25 softmax * 0.25 K-dup
                Sacc[h * 4 + j4] += e;
                if (g == 0) eS[(k * 8 + h * 4 + j4) * 17 + n] = e;
            }
        }
    }
    if (g == 0) {
#pragma unroll
        for (int jl = 0; jl < 8; ++jl)
            Sw[(w * 8 + jl) * 16 + n] = Sacc[jl];
    }
    __syncthreads();
    if (t < 128) {
        int jl = t >> 4, n2 = t & 15;
        float s = Sw[(0 * 8 + jl) * 16 + n2] + Sw[(1 * 8 + jl) * 16 + n2]
                + Sw[(2 * 8 + jl) * 16 + n2] + Sw[(3 * 8 + jl) * 16 + n2];
        rS[jl * 16 + n2] = __builtin_amdgcn_rcpf(s);
    }
    __syncthreads();

    // ---- Phase 2: sacc partial, c folded into B-operand; bf16 output ----
    float xf[2][8];
#pragma unroll
    for (int quad = 0; quad < 2; ++quad) {
        union { short8 v; short s[8]; } xr;
        int j = j0 + quad * 4 + g;
        xr.v = *(const short8*)(xbf + ((size_t)j * BB + b) * II);
#pragma unroll
        for (int i = 0; i < II; ++i) xf[quad][i] = bf2f(xr.s[i]);
    }

    for (int kk = 0; kk < 8; ++kk) {
        const int k = w * 8 + kk;
        floatx4 acc = {0.f, 0.f, 0.f, 0.f};
#pragma unroll
        for (int quad = 0; quad < 2; ++quad) {
            const int jl = quad * 4 + g;
            const int j  = j0 + jl;
            float bj = bias[(size_t)k * JJ + j];
            float c  = fmaf(eS[(k * 8 + jl) * 17 + n], rS[jl * 16 + n], bj);
            union { short8 v; short s[8]; } xs;
#pragma unroll
            for (int i = 0; i < II; ++i) {
                __hip_bfloat16 hv = __float2bfloat16(xf[quad][i] * c);
                __builtin_memcpy(&xs.s[i], &hv, 2);
            }
            short8 a = *(const short8*)(Wt + (((size_t)k * JJ + j) * ZZ + n) * II);
            acc = __builtin_amdgcn_mfma_f32_16x16x32_bf16(a, xs.v, acc, 0, 0, 0);
        }
        union { short4v v; short s[4]; } o;
#pragma unroll
        for (int r = 0; r < 4; ++r) {
            __hip_bfloat16 hv = __float2bfloat16(acc[r]);
            __builtin_memcpy(&o.s[r], &hv, 2);
        }
        *(short4v*)(sacc_p + SOFF(jt, k, g, b)) = o.v;
    }
}

// ---- Pass D: 144-way bf16 reduce + squash. 4-way jt-split + shfl combine ----
extern "C" __global__ __launch_bounds__(256)
void kD(const __hip_bfloat16* __restrict__ sacc_p, float* __restrict__ out) {
    int p  = blockIdx.x * 256 + threadIdx.x;   // [0, KK*BB*16)
    int r  = p & 3;
    int q  = (p >> 2) & 3;
    int kb = p >> 4;
    int k  = kb >> 7;
    int b  = kb & 127;

    floatx4 v = (floatx4){0.f, 0.f, 0.f, 0.f};
#pragma unroll 6
    for (int jt = r * 36; jt < r * 36 + 36; ++jt) {
        union { short4v sv; short s[4]; } u;
        u.sv = *(const short4v*)(sacc_p + SOFF(jt, k, q, b));
        v[0] += bf2f(u.s[0]);
        v[1] += bf2f(u.s[1]);
        v[2] += bf2f(u.s[2]);
        v[3] += bf2f(u.s[3]);
    }

#pragma unroll
    for (int c = 0; c < 4; ++c) {
        v[c] += __shfl_xor(v[c], 1);
        v[c] += __shfl_xor(v[c], 2);
    }

    float nsq = v[0] * v[0];
    nsq = fmaf(v[1], v[1], nsq);
    nsq = fmaf(v[2], v[2], nsq);
    nsq = fmaf(v[3], v[3], nsq);
    nsq += __shfl_xor(nsq, 4);
    nsq += __shfl_xor(nsq, 8);

    float nr = sqrtf(nsq);
    float scale = (1.f - 1.f / (__expf(nr) + 1e-20f)) / (nr + 1e-20f);
    if (r == 0) {
        floatx4 o = v * scale;
        *(floatx4*)(out + ((size_t)b * KK + k) * ZZ + q * 4) = o;
    }
}

extern "C" void kernel_launch(void* const* d_in, const int* in_sizes, int n_in,
                              void* d_out, int out_size, void* d_ws, size_t ws_size,
                              hipStream_t stream) {
    const float* x    = (const float*)d_in[0];
    const float* W    = (const float*)d_in[1];
    const float* bias = (const float*)d_in[2];
    float*       out  = (float*)d_out;

    float* ws     = (float*)d_ws;
    float* usum   = ws;
    float* usum_p = usum + N_USUM;
    __hip_bfloat16* sacc_p = (__hip_bfloat16*)(usum_p + N_USUMP);
    __hip_bfloat16* xbf    = sacc_p + N_SACCP;
    __hip_bfloat16* Wt     = xbf + (size_t)JJ * BB * II;

    // No memset: every workspace word is written before it is read.

    kP<<<KX_BLOCKS + KW_BLOCKS, 256, 0, stream>>>(x, W, xbf, Wt);
    kA<<<dim3(8, 8, NJG), 256, 0, stream>>>(xbf, Wt, usum_p);
    kR<<<(KK * BB * ZZ) / 256, 256, 0, stream>>>(usum_p, usum);
    kBC<<<dim3(NJT, 8), 256, 0, stream>>>(xbf, Wt, usum, bias, sacc_p);
    kD<<<(KK * BB * 16) / 256, 256, 0, stream>>>(sacc_p, out);
}